// Round 3
// baseline (151.976 us; speedup 1.0000x reference)
//
#include <hip/hip_runtime.h>

// ParametricBiquad DF2T, exact wave-level affine scan (no warmup redundancy).
//
// State s=(s1,s2): s' = M s + v*x, M = [[-a1,1],[-a2,0]].  A K=32 chunk is the
// affine map s_out = P s_in + f with P = M^32 (5 squarings) and f = chunk run
// from zero state (pass 1).  A 6-step Kogge-Stone shuffle scan over the wave's
// 64 lanes composes the maps -> each lane's exact entering state.  Lanes 0..7
// are history-only (256 samples of true warmup for lane 8 == R2 semantics,
// absmax 0.25); lanes 8..63 re-run their chunk from x kept in registers and
// store y (pass 2).  No LDS, no barriers; compute amplification 9x -> 2.3x.

constexpr int B_DIM = 64;
constexpr int L_DIM = 262144;
constexpr int K = 32;                        // samples per lane-chunk
constexpr int CPR = L_DIM / K;               // 8192 chunks per row
constexpr int OC = 56;                       // output chunks per wave (lanes 8..63)
constexpr int WPR = (CPR + OC - 1) / OC;     // 147 waves per row (146*56+16)
constexpr int TOTAL_WAVES = B_DIM * WPR;     // 9408
constexpr int T = 256;
constexpr int GRID = TOTAL_WAVES * 64 / T;   // 2352 blocks

#define BIQ_STEP(xs)                                            \
    do {                                                        \
        float yv_ = fmaf(b0, (xs), s1);                         \
        float t1_ = fmaf(b1, (xs), s2);                         \
        s2 = fmaf(-a2, yv_, b2 * (xs));                         \
        s1 = fmaf(-a1, yv_, t1_);                               \
    } while (0)

#define BIQ_STEP_Y(xs, yd)                                      \
    do {                                                        \
        (yd) = fmaf(b0, (xs), s1);                              \
        float t1_ = fmaf(b1, (xs), s2);                         \
        s2 = fmaf(-a2, (yd), b2 * (xs));                        \
        s1 = fmaf(-a1, (yd), t1_);                              \
    } while (0)

__global__ __launch_bounds__(T, 6) void biquad_wavescan(
    const float* __restrict__ x,
    const float* __restrict__ coeffs,
    float* __restrict__ y)
{
    const int gtid = blockIdx.x * T + threadIdx.x;
    const int gw   = gtid >> 6;          // global wave id
    const int lane = gtid & 63;
    const int row  = gw / WPR;
    const int w    = gw - row * WPR;
    const int c    = w * OC - 8 + lane;  // chunk index in row; may be <0 or >=CPR

    const float* cf = coeffs + row * 5;
    const float b0 = cf[0], b1 = cf[1], b2 = cf[2];
    const float a1 = cf[3], a2 = cf[4];

    const bool active = (c >= 0) && (c < CPR);

    // ---- pass 1: load chunk into registers, run from zero state -> f ----
    const float4* xp = (const float4*)(x + (size_t)row * L_DIM
                                         + (size_t)(active ? c : 0) * K);
    float4 xv[8];
    #pragma unroll
    for (int i = 0; i < 8; ++i) xv[i] = xp[i];

    float s1 = 0.f, s2 = 0.f;
    #pragma unroll
    for (int i = 0; i < 8; ++i) {
        BIQ_STEP(xv[i].x); BIQ_STEP(xv[i].y); BIQ_STEP(xv[i].z); BIQ_STEP(xv[i].w);
    }

    // ---- P = M^32 via 5 squarings; M = [[-a1,1],[-a2,0]] ----
    float p00 = -a1, p01 = 1.f, p10 = -a2, p11 = 0.f;
    #pragma unroll
    for (int i = 0; i < 5; ++i) {
        float q00 = fmaf(p00, p00, p01 * p10);
        float q01 = fmaf(p00, p01, p01 * p11);
        float q10 = fmaf(p10, p00, p11 * p10);
        float q11 = fmaf(p10, p01, p11 * p11);
        p00 = q00; p01 = q01; p10 = q10; p11 = q11;
    }

    float f1 = active ? s1 : 0.f;
    float f2 = active ? s2 : 0.f;
    if (!active) { p00 = 1.f; p01 = 0.f; p10 = 0.f; p11 = 1.f; }  // identity map

    // ---- Kogge-Stone inclusive scan of affine maps across the wave ----
    // compose: (Pc,fc) after (Pp,fp):  P = Pc*Pp ; f = Pc*fp + fc
    #pragma unroll
    for (int d = 1; d < 64; d <<= 1) {
        float q00 = __shfl_up(p00, d, 64);
        float q01 = __shfl_up(p01, d, 64);
        float q10 = __shfl_up(p10, d, 64);
        float q11 = __shfl_up(p11, d, 64);
        float g1  = __shfl_up(f1,  d, 64);
        float g2  = __shfl_up(f2,  d, 64);
        if (lane >= d) {
            float n00 = fmaf(p00, q00, p01 * q10);
            float n01 = fmaf(p00, q01, p01 * q11);
            float n10 = fmaf(p10, q00, p11 * q10);
            float n11 = fmaf(p10, q01, p11 * q11);
            f1 = fmaf(p00, g1, fmaf(p01, g2, f1));
            f2 = fmaf(p10, g1, fmaf(p11, g2, f2));
            p00 = n00; p01 = n01; p10 = n10; p11 = n11;
        }
    }

    // exclusive: state entering this lane's chunk (lane 0 never writes)
    float e1 = __shfl_up(f1, 1, 64);
    float e2 = __shfl_up(f2, 1, 64);

    // ---- pass 2: re-run chunk from exact state, store y ----
    if (lane >= 8 && c < CPR) {
        s1 = e1; s2 = e2;
        float4* yp = (float4*)(y + (size_t)row * L_DIM + (size_t)c * K);
        #pragma unroll
        for (int i = 0; i < 8; ++i) {
            float4 yv;
            BIQ_STEP_Y(xv[i].x, yv.x);
            BIQ_STEP_Y(xv[i].y, yv.y);
            BIQ_STEP_Y(xv[i].z, yv.z);
            BIQ_STEP_Y(xv[i].w, yv.w);
            yp[i] = yv;
        }
    }
}

extern "C" void kernel_launch(void* const* d_in, const int* in_sizes, int n_in,
                              void* d_out, int out_size, void* d_ws, size_t ws_size,
                              hipStream_t stream) {
    const float* x      = (const float*)d_in[0];
    const float* coeffs = (const float*)d_in[1];
    float*       yout   = (float*)d_out;

    biquad_wavescan<<<GRID, T, 0, stream>>>(x, coeffs, yout);
}

// Round 4
// 113.747 us; speedup vs baseline: 1.3361x; 1.3361x over previous
//
#include <hip/hip_runtime.h>

// ParametricBiquad DF2T, exact wave-level affine scan + LDS-bounced coalesced
// output stores.
//
// State s=(s1,s2): s' = M s + v*x, M = [[-a1,1],[-a2,0]].  A K=32 chunk is the
// affine map s_out = P s_in + f with P = M^32 (5 squarings) and f = chunk run
// from zero state (pass 1).  A 6-step Kogge-Stone shuffle scan composes the
// 64 lanes' maps -> each lane's exact entering state.  Lanes 0..7 are
// history-only (256 true-warmup samples for lane 8; absmax 0.25 measured);
// lanes 8..63 re-run their chunk (x held in registers) and write y.
//
// R4 fix (R3 post-mortem): per-lane scattered 16-B stores caused 2.3x HBM
// write amplification (partial-line RMW).  Outputs now bounce through a
// wave-private LDS region (stride-9-float4 swizzle, <=2-way conflicts) and
// are streamed out with consecutive lanes -> consecutive float4: whole-line,
// 1-KB-per-instruction coalesced stores.  No __syncthreads needed: LDS
// regions are disjoint per wave and waves are internally in-order.

constexpr int B_DIM = 64;
constexpr int L_DIM = 262144;
constexpr int K = 32;                        // samples per lane-chunk
constexpr int CPR = L_DIM / K;               // 8192 chunks per row
constexpr int OC = 56;                       // output chunks per wave (lanes 8..63)
constexpr int WPR = (CPR + OC - 1) / OC;     // 147 waves per row
constexpr int TOTAL_WAVES = B_DIM * WPR;     // 9408
constexpr int T = 256;
constexpr int WPB = T / 64;                  // 4 waves per block
constexpr int GRID = TOTAL_WAVES / WPB;      // 2352 blocks
constexpr int RS = 9;                        // LDS row stride in float4 (swizzle)
constexpr int WAVE_LDS = OC * RS;            // 504 float4 per wave

#define BIQ_STEP(xs)                                            \
    do {                                                        \
        float yv_ = fmaf(b0, (xs), s1);                         \
        float t1_ = fmaf(b1, (xs), s2);                         \
        s2 = fmaf(-a2, yv_, b2 * (xs));                         \
        s1 = fmaf(-a1, yv_, t1_);                               \
    } while (0)

#define BIQ_STEP_Y(xs, yd)                                      \
    do {                                                        \
        (yd) = fmaf(b0, (xs), s1);                              \
        float t1_ = fmaf(b1, (xs), s2);                         \
        s2 = fmaf(-a2, (yd), b2 * (xs));                        \
        s1 = fmaf(-a1, (yd), t1_);                              \
    } while (0)

__global__ __launch_bounds__(T) void biquad_wavescan2(
    const float* __restrict__ x,
    const float* __restrict__ coeffs,
    float* __restrict__ y)
{
    __shared__ float4 lds[WPB * WAVE_LDS];   // 4*504*16 = 32256 B

    const int gtid = blockIdx.x * T + threadIdx.x;
    const int gw   = gtid >> 6;          // global wave id
    const int lane = gtid & 63;
    const int row  = gw / WPR;
    const int w    = gw - row * WPR;
    const int c    = w * OC - 8 + lane;  // chunk index in row; may be <0 or >=CPR

    float4* wlds = &lds[(threadIdx.x >> 6) * WAVE_LDS];

    const float* cf = coeffs + row * 5;
    const float b0 = cf[0], b1 = cf[1], b2 = cf[2];
    const float a1 = cf[3], a2 = cf[4];

    const bool active = (c >= 0) && (c < CPR);

    // ---- pass 1: load chunk into registers, run from zero state -> f ----
    const float4* xp = (const float4*)(x + (size_t)row * L_DIM
                                         + (size_t)(active ? c : 0) * K);
    float4 xv[8];
    #pragma unroll
    for (int i = 0; i < 8; ++i) xv[i] = xp[i];

    float s1 = 0.f, s2 = 0.f;
    #pragma unroll
    for (int i = 0; i < 8; ++i) {
        BIQ_STEP(xv[i].x); BIQ_STEP(xv[i].y); BIQ_STEP(xv[i].z); BIQ_STEP(xv[i].w);
    }

    // ---- P = M^32 via 5 squarings; M = [[-a1,1],[-a2,0]] ----
    float p00 = -a1, p01 = 1.f, p10 = -a2, p11 = 0.f;
    #pragma unroll
    for (int i = 0; i < 5; ++i) {
        float q00 = fmaf(p00, p00, p01 * p10);
        float q01 = fmaf(p00, p01, p01 * p11);
        float q10 = fmaf(p10, p00, p11 * p10);
        float q11 = fmaf(p10, p01, p11 * p11);
        p00 = q00; p01 = q01; p10 = q10; p11 = q11;
    }

    float f1 = active ? s1 : 0.f;
    float f2 = active ? s2 : 0.f;
    if (!active) { p00 = 1.f; p01 = 0.f; p10 = 0.f; p11 = 1.f; }  // identity

    // ---- Kogge-Stone inclusive scan of affine maps across the wave ----
    #pragma unroll
    for (int d = 1; d < 64; d <<= 1) {
        float q00 = __shfl_up(p00, d, 64);
        float q01 = __shfl_up(p01, d, 64);
        float q10 = __shfl_up(p10, d, 64);
        float q11 = __shfl_up(p11, d, 64);
        float g1  = __shfl_up(f1,  d, 64);
        float g2  = __shfl_up(f2,  d, 64);
        if (lane >= d) {
            float n00 = fmaf(p00, q00, p01 * q10);
            float n01 = fmaf(p00, q01, p01 * q11);
            float n10 = fmaf(p10, q00, p11 * q10);
            float n11 = fmaf(p10, q01, p11 * q11);
            f1 = fmaf(p00, g1, fmaf(p01, g2, f1));
            f2 = fmaf(p10, g1, fmaf(p11, g2, f2));
            p00 = n00; p01 = n01; p10 = n10; p11 = n11;
        }
    }

    // exclusive: state entering this lane's chunk
    float e1 = __shfl_up(f1, 1, 64);
    float e2 = __shfl_up(f2, 1, 64);

    // ---- pass 2: re-run chunk from exact state, write y into wave LDS ----
    if (lane >= 8 && c < CPR) {
        s1 = e1; s2 = e2;
        float4* wp = &wlds[(lane - 8) * RS];
        #pragma unroll
        for (int i = 0; i < 8; ++i) {
            float4 yv;
            BIQ_STEP_Y(xv[i].x, yv.x);
            BIQ_STEP_Y(xv[i].y, yv.y);
            BIQ_STEP_Y(xv[i].z, yv.z);
            BIQ_STEP_Y(xv[i].w, yv.w);
            wp[i] = yv;
        }
    }

    // ---- coalesced global store: consecutive lanes -> consecutive float4 ----
    // wave-synchronous; compiler orders ds_write -> ds_read via lgkmcnt
    const int first = w * OC;                          // first output chunk
    int nvalid = CPR - first; if (nvalid > OC) nvalid = OC;
    float4* ydst = (float4*)(y + (size_t)row * L_DIM) + first * (K / 4);
    for (int g = lane; g < nvalid * 8; g += 64) {
        ydst[g] = wlds[(g >> 3) * RS + (g & 7)];
    }
}

extern "C" void kernel_launch(void* const* d_in, const int* in_sizes, int n_in,
                              void* d_out, int out_size, void* d_ws, size_t ws_size,
                              hipStream_t stream) {
    const float* x      = (const float*)d_in[0];
    const float* coeffs = (const float*)d_in[1];
    float*       yout   = (float*)d_out;

    biquad_wavescan2<<<GRID, T, 0, stream>>>(x, coeffs, yout);
}

// Round 5
// 112.716 us; speedup vs baseline: 1.3483x; 1.0091x over previous
//
#include <hip/hip_runtime.h>

// ParametricBiquad DF2T, exact wave-level affine scan, fully-coalesced I/O.
//
// State s=(s1,s2): s' = M s + v*x, M = [[-a1,1],[-a2,0]].  A K=32 chunk is the
// affine map s_out = P s_in + f with P = M^32 (5 squarings) and f = chunk run
// from zero state (pass 1).  A 6-step Kogge-Stone shuffle scan composes the
// 64 lanes' maps -> each lane's exact entering state.  Lanes 0..7 are
// history-only (256 true-warmup samples for lane 8; absmax 0.25 measured);
// lanes 8..63 re-run their chunk (x held in registers) and write y.
//
// R4 fixed write amplification (LDS-bounced coalesced stores: WRITE 148->64MB).
// R5 fixes the read path: pass-1 used 128-B-stride gathers (64 cache lines per
// load instr = 8x L1 request traffic, ~8 us of tag-lookup serialization).
// Now each wave stages its 8-KB region into wave-private LDS with coalesced
// float4 loads, and lanes read their chunks via ds_read_b128 from a
// stride-9-float4 swizzled layout.  No __syncthreads anywhere: LDS regions are
// wave-private and waves are internally in-order (R4 validated this).

constexpr int B_DIM = 64;
constexpr int L_DIM = 262144;
constexpr int K = 32;                        // samples per lane-chunk (= one 128-B line)
constexpr int CPR = L_DIM / K;               // 8192 chunks per row
constexpr int OC = 56;                       // output chunks per wave (lanes 8..63)
constexpr int WPR = (CPR + OC - 1) / OC;     // 147 waves per row
constexpr int TOTAL_WAVES = B_DIM * WPR;     // 9408
constexpr int T = 256;
constexpr int WPB = T / 64;                  // 4 waves per block
constexpr int GRID = TOTAL_WAVES / WPB;      // 2352 blocks
constexpr int RS = 9;                        // LDS row stride in float4 (swizzle)
constexpr int ROWS = 64;                     // 8 halo + 56 output rows per wave
constexpr int WAVE_LDS = ROWS * RS;          // 576 float4 = 9216 B per wave
constexpr int ROW_F4 = L_DIM / 4;            // 65536 float4 per batch row

#define BIQ_STEP(xs)                                            \
    do {                                                        \
        float yv_ = fmaf(b0, (xs), s1);                         \
        float t1_ = fmaf(b1, (xs), s2);                         \
        s2 = fmaf(-a2, yv_, b2 * (xs));                         \
        s1 = fmaf(-a1, yv_, t1_);                               \
    } while (0)

#define BIQ_STEP_Y(xs, yd)                                      \
    do {                                                        \
        (yd) = fmaf(b0, (xs), s1);                              \
        float t1_ = fmaf(b1, (xs), s2);                         \
        s2 = fmaf(-a2, (yd), b2 * (xs));                        \
        s1 = fmaf(-a1, (yd), t1_);                              \
    } while (0)

__global__ __launch_bounds__(T) void biquad_wavescan3(
    const float* __restrict__ x,
    const float* __restrict__ coeffs,
    float* __restrict__ y)
{
    __shared__ float4 lds[WPB * WAVE_LDS];   // 4*9216 = 36864 B -> 4 blocks/CU

    const int gtid = blockIdx.x * T + threadIdx.x;
    const int gw   = gtid >> 6;          // global wave id
    const int lane = gtid & 63;
    const int row  = gw / WPR;           // batch row
    const int w    = gw - row * WPR;     // wave index within row
    const int c    = w * OC - 8 + lane;  // chunk index; may be <0 or >=CPR

    float4* wlds = &lds[(threadIdx.x >> 6) * WAVE_LDS];

    // ---- stage wave's 64-chunk region into LDS, coalesced ----
    const float4* xrow = (const float4*)(x + (size_t)row * L_DIM);
    const int rbase = (w * OC - 8) * (K / 4);     // f4 index of region start
    #pragma unroll
    for (int j = 0; j < 8; ++j) {
        int f = j * 64 + lane;                    // 0..511 within region
        int src = rbase + f;
        src = src < 0 ? 0 : (src >= ROW_F4 ? ROW_F4 - 1 : src);  // edge waves: garbage-but-safe
        wlds[(f >> 3) * RS + (f & 7)] = xrow[src];
    }

    const float* cf = coeffs + row * 5;
    const float b0 = cf[0], b1 = cf[1], b2 = cf[2];
    const float a1 = cf[3], a2 = cf[4];

    const bool active = (c >= 0) && (c < CPR);

    // ---- lane reads own chunk (row `lane`) from LDS into registers ----
    float4 xv[8];
    {
        const float4* rp = &wlds[lane * RS];
        #pragma unroll
        for (int j = 0; j < 8; ++j) xv[j] = rp[j];
    }

    // ---- pass 1: run chunk from zero state -> f ----
    float s1 = 0.f, s2 = 0.f;
    #pragma unroll
    for (int i = 0; i < 8; ++i) {
        BIQ_STEP(xv[i].x); BIQ_STEP(xv[i].y); BIQ_STEP(xv[i].z); BIQ_STEP(xv[i].w);
    }

    // ---- P = M^32 via 5 squarings; M = [[-a1,1],[-a2,0]] ----
    float p00 = -a1, p01 = 1.f, p10 = -a2, p11 = 0.f;
    #pragma unroll
    for (int i = 0; i < 5; ++i) {
        float q00 = fmaf(p00, p00, p01 * p10);
        float q01 = fmaf(p00, p01, p01 * p11);
        float q10 = fmaf(p10, p00, p11 * p10);
        float q11 = fmaf(p10, p01, p11 * p11);
        p00 = q00; p01 = q01; p10 = q10; p11 = q11;
    }

    float f1 = active ? s1 : 0.f;
    float f2 = active ? s2 : 0.f;
    if (!active) { p00 = 1.f; p01 = 0.f; p10 = 0.f; p11 = 1.f; }  // identity

    // ---- Kogge-Stone inclusive scan of affine maps across the wave ----
    #pragma unroll
    for (int d = 1; d < 64; d <<= 1) {
        float q00 = __shfl_up(p00, d, 64);
        float q01 = __shfl_up(p01, d, 64);
        float q10 = __shfl_up(p10, d, 64);
        float q11 = __shfl_up(p11, d, 64);
        float g1  = __shfl_up(f1,  d, 64);
        float g2  = __shfl_up(f2,  d, 64);
        if (lane >= d) {
            float n00 = fmaf(p00, q00, p01 * q10);
            float n01 = fmaf(p00, q01, p01 * q11);
            float n10 = fmaf(p10, q00, p11 * q10);
            float n11 = fmaf(p10, q01, p11 * q11);
            f1 = fmaf(p00, g1, fmaf(p01, g2, f1));
            f2 = fmaf(p10, g1, fmaf(p11, g2, f2));
            p00 = n00; p01 = n01; p10 = n10; p11 = n11;
        }
    }

    // exclusive: state entering this lane's chunk
    float e1 = __shfl_up(f1, 1, 64);
    float e2 = __shfl_up(f2, 1, 64);

    // ---- pass 2: re-run chunk from exact state, write y into own LDS row ----
    if (lane >= 8 && c < CPR) {
        s1 = e1; s2 = e2;
        float4* wp = &wlds[lane * RS];   // overwrite own x row in place
        #pragma unroll
        for (int i = 0; i < 8; ++i) {
            float4 yv;
            BIQ_STEP_Y(xv[i].x, yv.x);
            BIQ_STEP_Y(xv[i].y, yv.y);
            BIQ_STEP_Y(xv[i].z, yv.z);
            BIQ_STEP_Y(xv[i].w, yv.w);
            wp[i] = yv;
        }
    }

    // ---- coalesced global store: consecutive lanes -> consecutive float4 ----
    const int first = w * OC;                          // first output chunk
    int nvalid = CPR - first; if (nvalid > OC) nvalid = OC;
    float4* ydst = (float4*)(y + (size_t)row * L_DIM) + first * (K / 4);
    for (int g = lane; g < nvalid * 8; g += 64) {
        ydst[g] = wlds[((g >> 3) + 8) * RS + (g & 7)];
    }
}

extern "C" void kernel_launch(void* const* d_in, const int* in_sizes, int n_in,
                              void* d_out, int out_size, void* d_ws, size_t ws_size,
                              hipStream_t stream) {
    const float* x      = (const float*)d_in[0];
    const float* coeffs = (const float*)d_in[1];
    float*       yout   = (float*)d_out;

    biquad_wavescan3<<<GRID, T, 0, stream>>>(x, coeffs, yout);
}